// Round 4
// baseline (596.634 us; speedup 1.0000x reference)
//
#include <hip/hip_runtime.h>
#include <stdint.h>

// y[t][o] = sum_i x[t][i] * ((w_pos[o][i]>0) - (w_neg[o][i]>0))
// One bf16 GEMM vs ternary weights (ternary is exact in bf16).
// M=8192, N=4096, K=4096. fp32 out.
// ws: [0,64MiB) x_bf16 ; [64MiB,96MiB) tern_bf16.
//
// GEMM: 256x256 tile, BK=64, 8 waves (2Mx4N), 128 KiB LDS double buffer.
// NEW this round: LDS stored in MFMA-FRAGMENT ORDER — every ds_read_b128
// is base + lane*16 (fully linear, the provably-minimal LDS pattern; same
// as the DMA writes). The fragment permutation is applied on the per-lane
// GLOBAL source address of global_load_lds (global side is per-lane;
// LDS side stays linear). Global coalescing unchanged (16 rows x 64B
// contiguous per staging instruction). Banked 8-phase pipeline kept;
// vmcnt(6) at phase top (publish bound: barrier@T publishes stages<=T-4;
// all reads are stage+5).

#define TOKENS 8192
#define DIN    4096
#define DOUT   4096

typedef __bf16  bf16x8  __attribute__((ext_vector_type(8)));
typedef float   floatx4 __attribute__((ext_vector_type(4)));

__device__ __forceinline__ void async_copy16(const void* g, void* l) {
  __builtin_amdgcn_global_load_lds(
      (const __attribute__((address_space(1))) void*)g,
      (__attribute__((address_space(3))) void*)l, 16, 0, 0);
}

__device__ __forceinline__ unsigned short f2bf_rne(float f) {
  union { float f; uint32_t u; } v; v.f = f;
  uint32_t u = v.u;
  u += 0x7fffu + ((u >> 16) & 1u);
  return (unsigned short)(u >> 16);
}

__device__ __forceinline__ unsigned short tern_bits(float p, float n) {
  bool bp = p > 0.0f, bn = n > 0.0f;
  return (unsigned short)(bp == bn ? 0u : (bp ? 0x3f80u : 0xbf80u));
}

// Fused prep: blocks [0,8192) convert x fp32->bf16; blocks [8192,12288)
// ternarize w. Both memory-bound, one launch.
__global__ __launch_bounds__(256) void prep_kernel(
    const float4* __restrict__ x, ushort4* __restrict__ xb,
    const float4* __restrict__ wp, const float4* __restrict__ wn,
    ushort4* __restrict__ t) {
  const uint32_t bid = blockIdx.x;
  if (bid < 8192u) {
    const uint32_t stride = 8192u * 256u;
    uint32_t i = bid * 256u + threadIdx.x;
#pragma unroll
    for (int it = 0; it < 4; ++it, i += stride) {
      float4 v = x[i];
      ushort4 o;
      o.x = f2bf_rne(v.x); o.y = f2bf_rne(v.y);
      o.z = f2bf_rne(v.z); o.w = f2bf_rne(v.w);
      xb[i] = o;
    }
  } else {
    const uint32_t stride = 4096u * 256u;
    uint32_t i = (bid - 8192u) * 256u + threadIdx.x;
#pragma unroll
    for (int it = 0; it < 4; ++it, i += stride) {
      float4 p = wp[i];
      float4 n = wn[i];
      ushort4 o;
      o.x = tern_bits(p.x, n.x);
      o.y = tern_bits(p.y, n.y);
      o.z = tern_bits(p.z, n.z);
      o.w = tern_bits(p.w, n.w);
      t[i] = o;
    }
  }
}

// ---------------------------------------------------------------------------
// GEMM C[M,N] = A[M,K] * B[N,K]^T, bf16 in, fp32 out.
//
// LDS map (per buffer b in {0,1}, base b*65536):
//   A at +0, B at +32768. Each tile = [kc in 2][16 KiB region].
//   Region layout = FRAGMENT ORDER: [sub-tile st 0..15][lane 0..63][16B],
//   where fragment lane l of sub-tile st holds
//     row (st*16 + (l&15)), k-elems kc*32 + (l>>4)*8 .. +8  (16 bytes).
//   => fragment ds_read = base + st*1024 + lane*16 (LINEAR).
// Staging thread t, load j: LDS offset o = t*16 + j*8192 of the region;
//   st = o>>10, l = (o>>4)&63 -> global row bm|bn + st*16 + (l&15),
//   col bytes KB + kc*64 + ((l>>4)&3)*16. Per-instruction global pattern:
//   16 rows x 64B contiguous (same coalescing as before).
//
// Phase P (banked pipeline, R3 schedule):
//   [ lgkmcnt(0)   -- prev phase's 6 reads retired
//     vmcnt(6)     -- publish bound: stages <= P-4 retired in EVERY wave
//                     at the preceding barrier => reads at P (all stage+5) safe
//     issue 6 linear ds_read_b128 (4 A + 2 B-half) for P+1/P+2
//     16 MFMA on banks read at P-1 (LDS services new reads underneath)
//     stage 2 global_load_lds
//     s_barrier ]
// Stage map: Ph1:b1.Ak1(T2i+1) Ph2:b0.Bk0 Ph3:b0.Ak0 Ph4:b0.Bk1
//   Ph5:b0.Ak1 (T2i+2) Ph6:b1.Bk0 Ph7:b1.Ak0 Ph8:b1.Bk1 (T2i+3).
// Read map: Ph1: a1<-b0.Ak0.mh1, b1[01]<-b0.Bk1 | Ph2: a0<-b0.Ak1.mh0, b1[23]
//   Ph3: a1<-b0.Ak1.mh1, b0[01]<-b1.Bk0 | Ph4: a0<-b1.Ak0.mh0, b0[23]
//   Ph5: a1<-b1.Ak0.mh1, b1[01]<-b1.Bk1 | Ph6: a0<-b1.Ak1.mh0, b1[23]
//   Ph7: a1<-b1.Ak1.mh1, b0[01]<-b0.Bk0'| Ph8: a0<-b0.Ak0'.mh0, b0[23]
// All read regions are exactly 5 phases after their stage; vm6 at top of
// P retires stages <= P-4 per wave, so the barrier ending P publishes
// them CU-wide one phase before use. WAR: each staged region's last
// ds_read retired (lgkm0) >= 1 barrier before its overwrite issues.
// ---------------------------------------------------------------------------

#define LDS_BUF   65536u
#define LDS_B_OFF 32768u
#define LDS_KC    16384u

__global__ __launch_bounds__(512, 2) void gemm_bt(
    const unsigned short* __restrict__ A,   // [TOKENS][DIN] bf16
    const unsigned short* __restrict__ B,   // [DOUT][DIN]   bf16 ternary
    float* __restrict__ C)                  // [TOKENS][DOUT] fp32
{
  __shared__ __align__(16) char lds[131072];

  const int tid   = threadIdx.x;
  const int lane  = tid & 63;
  const int wid   = tid >> 6;
  const int waveM = wid >> 2;   // 0..1
  const int waveN = wid & 3;    // 0..3

  // Bijective XCD swizzle: 512 blocks = 8 XCDs x 64 contiguous tiles.
  const uint32_t flat = blockIdx.x;
  const uint32_t swz  = ((flat & 7u) << 6) | (flat >> 3);
  const uint32_t bm = (swz >> 4) * 256u;    // 0..31 -> M
  const uint32_t bn = (swz & 15u) * 256u;   // 0..15 -> N

  // Staging constants. Thread t covers region offsets t*16 (j=0) and
  // t*16+8192 (j=1). j=0 -> sub-tiles 0..7 (rows 0..127); j=1 adds 128 rows.
  const uint32_t st0   = (uint32_t)(tid >> 6);          // sub-tile 0..7 (j=0)
  const uint32_t frow  = (uint32_t)(tid & 15);
  const uint32_t fcol  = ((uint32_t)(tid >> 4) & 3u) * 16u;
  const uint32_t stA0  = (bm + st0 * 16u + frow) * 8192u + fcol;  // j=0
  const uint32_t stB0  = (bn + st0 * 16u + frow) * 8192u + fcol;
  const uint32_t tOff  = (uint32_t)tid * 16u;           // LDS byte offset j=0
  const char* Ab = (const char*)A;
  const char* Bb = (const char*)B;

  // Fragment read bases (linear: + lane*16).
  const uint32_t ldsBase =
      (uint32_t)(uintptr_t)(__attribute__((address_space(3))) char*)lds;
  const uint32_t aR0 = ldsBase + (uint32_t)waveM * 8192u + (uint32_t)lane * 16u;
  const uint32_t aR1 = aR0 + LDS_BUF;
  const uint32_t bR0 = ldsBase + LDS_B_OFF + (uint32_t)waveN * 4096u
                     + (uint32_t)lane * 16u;
  const uint32_t bR1 = bR0 + LDS_BUF;

  floatx4 acc[8][4];
#pragma unroll
  for (int m = 0; m < 8; ++m)
#pragma unroll
    for (int n = 0; n < 4; ++n)
      acc[m][n] = (floatx4)0.0f;

  // Double-banked fragments (asm outputs; 128-bit each).
  floatx4 a0f[4], a1f[4], b0f[4], b1f[4];

#define DSR(DST, ADDR, IMM)                                                \
  asm volatile("ds_read_b128 %0, %1 offset:%c2"                            \
               : "=v"(DST) : "v"(ADDR), "i"(IMM))

  // A: 4 sub-tiles (mh*4 + 0..3) of buf/kc.  imm <= 16384+7168 < 64K.
#define IA4(DST, ADDR, KC, MH) do {                                        \
    DSR(DST[0], ADDR, (KC) * 16384 + ((MH) * 4 + 0) * 1024);               \
    DSR(DST[1], ADDR, (KC) * 16384 + ((MH) * 4 + 1) * 1024);               \
    DSR(DST[2], ADDR, (KC) * 16384 + ((MH) * 4 + 2) * 1024);               \
    DSR(DST[3], ADDR, (KC) * 16384 + ((MH) * 4 + 3) * 1024);               \
  } while (0)

#define IB2(DST, N0, ADDR, KC) do {                                        \
    DSR(DST[N0],     ADDR, (KC) * 16384 + ((N0)) * 1024);                  \
    DSR(DST[N0 + 1], ADDR, (KC) * 16384 + ((N0) + 1) * 1024);              \
  } while (0)

#define STAGE_A(BUF, KC, KB) do {                                          \
    uint32_t g_ = stA0 + (KB) + (KC) * 64u;                                \
    uint32_t l_ = (BUF) * LDS_BUF + (KC) * LDS_KC + tOff;                  \
    async_copy16(Ab + g_,            lds + l_);                            \
    async_copy16(Ab + g_ + 1048576u, lds + l_ + 8192u);                    \
  } while (0)

#define STAGE_B(BUF, KC, KB) do {                                          \
    uint32_t g_ = stB0 + (KB) + (KC) * 64u;                                \
    uint32_t l_ = (BUF) * LDS_BUF + LDS_B_OFF + (KC) * LDS_KC + tOff;      \
    async_copy16(Bb + g_,            lds + l_);                            \
    async_copy16(Bb + g_ + 1048576u, lds + l_ + 8192u);                    \
  } while (0)

#define PHASE(MH, AF, BF, ISSUE_STMT, STAGE_STMT) do {                     \
    asm volatile("s_waitcnt lgkmcnt(0)" ::: "memory");                     \
    asm volatile("s_waitcnt vmcnt(6)" ::: "memory");                       \
    __builtin_amdgcn_sched_barrier(0);                                     \
    ISSUE_STMT;                                                            \
    __builtin_amdgcn_sched_barrier(0);                                     \
    __builtin_amdgcn_s_setprio(1);                                         \
    _Pragma("unroll")                                                      \
    for (int m_ = 0; m_ < 4; ++m_)                                         \
      _Pragma("unroll")                                                    \
      for (int n_ = 0; n_ < 4; ++n_)                                       \
        acc[(MH) * 4 + m_][n_] = __builtin_amdgcn_mfma_f32_16x16x32_bf16(  \
            __builtin_bit_cast(bf16x8, AF[m_]),                            \
            __builtin_bit_cast(bf16x8, BF[n_]),                            \
            acc[(MH) * 4 + m_][n_], 0, 0, 0);                              \
    __builtin_amdgcn_s_setprio(0);                                         \
    STAGE_STMT;                                                            \
    __builtin_amdgcn_s_barrier();                                          \
  } while (0)

  // Prologue: 7 regions staged in steady-state order (loads 1..14).
  STAGE_B(0, 0, 0u);    // loads 1-2   b0.Bk0
  STAGE_A(0, 0, 0u);    // loads 3-4   b0.Ak0
  STAGE_B(0, 1, 0u);    // loads 5-6   b0.Bk1
  STAGE_A(0, 1, 0u);    // loads 7-8   b0.Ak1
  STAGE_B(1, 0, 128u);  // loads 9-10  b1.Bk0
  STAGE_A(1, 0, 128u);  // loads 11-12 b1.Ak0
  STAGE_B(1, 1, 128u);  // loads 13-14 b1.Bk1
  asm volatile("s_waitcnt vmcnt(8)" ::: "memory");   // loads 1-6 retired
  __builtin_amdgcn_s_barrier();                      // ...and published
  // Prime bank for Ph1's MFMA: b0f <- b0.B.kc0, a0f <- b0.A.kc0.mh0.
  IB2(b0f, 0, bR0, 0); IB2(b0f, 2, bR0, 0);
  IA4(a0f, aR0, 0, 0);

#pragma unroll 1
  for (int i = 0; i < 32; ++i) {
    const uint32_t kb1 = (uint32_t)(2 * i + 1) * 128u;
    const uint32_t kb2 = (uint32_t)((2 * i + 2) & 63) * 128u;  // wraps: valid mem, never read
    const uint32_t kb3 = (uint32_t)((2 * i + 3) & 63) * 128u;

    PHASE(0, a0f, b0f, { IA4(a1f, aR0, 0, 1); IB2(b1f, 0, bR0, 1); },
          STAGE_A(1, 1, kb1));                                            // Ph1
    PHASE(1, a1f, b0f, { IA4(a0f, aR0, 1, 0); IB2(b1f, 2, bR0, 1); },
          STAGE_B(0, 0, kb2));                                            // Ph2
    PHASE(0, a0f, b1f, { IA4(a1f, aR0, 1, 1); IB2(b0f, 0, bR1, 0); },
          STAGE_A(0, 0, kb2));                                            // Ph3
    PHASE(1, a1f, b1f, { IA4(a0f, aR1, 0, 0); IB2(b0f, 2, bR1, 0); },
          STAGE_B(0, 1, kb2));                                            // Ph4
    PHASE(0, a0f, b0f, { IA4(a1f, aR1, 0, 1); IB2(b1f, 0, bR1, 1); },
          STAGE_A(0, 1, kb2));                                            // Ph5
    PHASE(1, a1f, b0f, { IA4(a0f, aR1, 1, 0); IB2(b1f, 2, bR1, 1); },
          STAGE_B(1, 0, kb3));                                            // Ph6
    PHASE(0, a0f, b1f, { IA4(a1f, aR1, 1, 1); IB2(b0f, 0, bR0, 0); },
          STAGE_A(1, 0, kb3));                                            // Ph7
    PHASE(1, a1f, b1f, { IA4(a0f, aR0, 0, 0); IB2(b0f, 2, bR0, 0); },
          STAGE_B(1, 1, kb3));                                            // Ph8
  }

  // C/D layout: col = lane&15, row = (lane>>4)*4 + reg.
  const int col0 = (int)bn + waveN * 64 + (lane & 15);
  const int row0 = (int)bm + waveM * 128 + (lane >> 4) * 4;
  float* Cp = C + (size_t)row0 * DOUT + col0;
#pragma unroll
  for (int m = 0; m < 8; ++m)
#pragma unroll
    for (int n = 0; n < 4; ++n)
#pragma unroll
      for (int r = 0; r < 4; ++r)
        Cp[(size_t)(m * 16 + r) * DOUT + n * 16] = acc[m][n][r];

#undef DSR
#undef IA4
#undef IB2
#undef STAGE_A
#undef STAGE_B
#undef PHASE
}

extern "C" void kernel_launch(void* const* d_in, const int* in_sizes, int n_in,
                              void* d_out, int out_size, void* d_ws, size_t ws_size,
                              hipStream_t stream) {
  const float* x  = (const float*)d_in[0];   // [8192, 4096] fp32
  const float* wp = (const float*)d_in[1];   // [4096, 4096] fp32
  const float* wn = (const float*)d_in[2];   // [4096, 4096] fp32
  float* out = (float*)d_out;                // [8192, 4096] fp32

  unsigned short* xb   = (unsigned short*)d_ws;
  unsigned short* tern = xb + (size_t)TOKENS * DIN;

  // Fused prep: 8192 cvt blocks + 4096 tern blocks.
  prep_kernel<<<12288, 256, 0, stream>>>(
      (const float4*)x, (ushort4*)xb,
      (const float4*)wp, (const float4*)wn, (ushort4*)tern);

  // 512 blocks (1D, XCD-swizzled in-kernel) x 512 threads.
  gemm_bt<<<TOKENS / 256 * (DOUT / 256), 512, 0, stream>>>(xb, tern, out);
}

// Round 9
// 528.511 us; speedup vs baseline: 1.1289x; 1.1289x over previous
//
#include <hip/hip_runtime.h>
#include <hip/hip_cooperative_groups.h>
#include <stdint.h>

namespace cg = cooperative_groups;

// y[t][o] = sum_i x[t][i] * ((w_pos[o][i]>0) - (w_neg[o][i]>0))
// Single COOPERATIVE kernel: per-block prep slice -> cg::grid().sync()
// -> two 256x256 GEMM tiles (verified R3 pipeline, 237us).
// M=8192, N=4096, K=4096. fp32 out.
// ws: [0,64MiB) x_bf16 ; [64MiB,96MiB) tern_bf16.
//
// R8 post-mortem: R5-R8's NaN was NOT the grid barrier — it was a botched
// merge of the LDS staging offset. R3 (verified): ldsSt = (tid>>6)*2048 +
// (tid&63)*16 (wave owns 2KiB span; +1024 second copy fills upper half).
// R5-R8 had ldsSt = tid*16 (from R4's layout experiment): waves overlap
// pairwise and bytes [9216,16384) of every region are never written ->
// poison LDS -> NaN. Fixed here; cooperative sync retained (supported,
// proven to launch+complete under the harness in R8).

#define TOKENS 8192
#define DIN    4096
#define DOUT   4096

typedef __bf16  bf16x8  __attribute__((ext_vector_type(8)));
typedef float   floatx4 __attribute__((ext_vector_type(4)));
typedef float   f32x4   __attribute__((ext_vector_type(4)));
typedef unsigned short u16x4 __attribute__((ext_vector_type(4)));

__device__ __forceinline__ void async_copy16(const void* g, void* l) {
  __builtin_amdgcn_global_load_lds(
      (const __attribute__((address_space(1))) void*)g,
      (__attribute__((address_space(3))) void*)l, 16, 0, 0);
}

__device__ __forceinline__ unsigned short f2bf_rne(float f) {
  union { float f; uint32_t u; } v; v.f = f;
  uint32_t u = v.u;
  u += 0x7fffu + ((u >> 16) & 1u);
  return (unsigned short)(u >> 16);
}

__device__ __forceinline__ unsigned short tern_bits(float p, float n) {
  bool bp = p > 0.0f, bn = n > 0.0f;
  return (unsigned short)(bp == bn ? 0u : (bp ? 0x3f80u : 0xbf80u));
}

// ---------------------------------------------------------------------------
// GEMM section: LDS map (per buffer b in {0,1}, base b*65536): A at +0,
// B at +32768; each tile [kc in 2][256 rows][64B row]. Chunk swizzle:
// 64-B row = 4 chunks of 16 B; chunk c stored at slot c ^ ((row>>1)&3).
// Applied on pre-swizzled GLOBAL source (staging keeps linear lane->LDS)
// and on LDS read address. Conflict-free (2-way max).
//
// Staging: thread t covers region rows srow = (t>>6)*32 + ((t&63)>>2)
// (first copy) and srow+16 (second copy, +131072 global / +1024 LDS),
// slot = t&3. Wave w writes exactly [w*2048, w*2048+2048) of the region.
//
// Phase P: [ lgkmcnt(0) (prev 6 reads retired); vmcnt(8) (RAW horizon:
//   retires stage of P-5); issue 6 asm ds_read_b128 (4A + 2B-half) for
//   P+1/P+2; 16 MFMA on banks read at P-1 (LDS services reads underneath);
//   stage 2 global_load_lds; s_barrier ].
// Stage map: Ph1:b1.Ak1(T2i+1) Ph2:b0.Bk0 Ph3:b0.Ak0 Ph4:b0.Bk1
//   Ph5:b0.Ak1 (T2i+2) Ph6:b1.Bk0 Ph7:b1.Ak0 Ph8:b1.Bk1 (T2i+3).
// Tile boundary: lgkmcnt(0)+vmcnt(0)+barrier drains dangling Ph8 reads and
// in-flight garbage stages before the next prologue overwrites regions.
// ---------------------------------------------------------------------------

#define LDS_BUF   65536u
#define LDS_B_OFF 32768u
#define LDS_KC    16384u

__global__ __launch_bounds__(512, 2) void fused_kernel(
    const float* __restrict__ x,    // [8192,4096] fp32
    const float* __restrict__ wp,   // [4096,4096] fp32
    const float* __restrict__ wn,   // [4096,4096] fp32
    unsigned short* __restrict__ xb,    // ws: bf16 x
    unsigned short* __restrict__ tern,  // ws: bf16 ternary
    float* __restrict__ C)          // [8192,4096] fp32
{
  __shared__ __align__(16) char lds[131072];

  const int tid = threadIdx.x;
  const uint32_t b = blockIdx.x;   // 0..255

  // ===== prep slice: 1/256 of cvt(x) and tern(wp,wn) =====
  {
    const f32x4* xf = (const f32x4*)x;
    u16x4* xo = (u16x4*)xb;
    uint32_t i = b * 32768u + (uint32_t)tid;   // 8.39M float4 total
#pragma unroll 4
    for (int j = 0; j < 64; ++j, i += 512u) {
      f32x4 v = __builtin_nontemporal_load(&xf[i]);
      u16x4 o;
      o.x = f2bf_rne(v.x); o.y = f2bf_rne(v.y);
      o.z = f2bf_rne(v.z); o.w = f2bf_rne(v.w);
      xo[i] = o;                      // normal store: keep L2/L3-resident
    }
    const f32x4* wpf = (const f32x4*)wp;
    const f32x4* wnf = (const f32x4*)wn;
    u16x4* to = (u16x4*)tern;
    uint32_t k = b * 16384u + (uint32_t)tid;   // 4.19M pair-indices total
#pragma unroll 4
    for (int j = 0; j < 32; ++j, k += 512u) {
      f32x4 p = __builtin_nontemporal_load(&wpf[k]);
      f32x4 n = __builtin_nontemporal_load(&wnf[k]);
      u16x4 o;
      o.x = tern_bits(p.x, n.x);
      o.y = tern_bits(p.y, n.y);
      o.z = tern_bits(p.z, n.z);
      o.w = tern_bits(p.w, n.w);
      to[k] = o;                      // normal store
    }
  }

  // ===== supported grid-wide barrier (cooperative launch) =====
  asm volatile("s_waitcnt vmcnt(0) lgkmcnt(0)" ::: "memory");
  cg::this_grid().sync();
  __builtin_amdgcn_sched_barrier(0);   // nothing hoists above the barrier

  // ===== GEMM: two tiles per block (verified R3 pipeline) =====
  const int lane  = tid & 63;
  const int wid   = tid >> 6;
  const int waveM = wid >> 2;   // 0..1
  const int waveN = wid & 3;    // 0..3

  const int mrow = lane & 15;
  const int q    = lane >> 4;
  const int xs   = (q ^ ((mrow >> 1) & 3)) * 16;
  const uint32_t ldsBase =
      (uint32_t)(uintptr_t)(__attribute__((address_space(3))) char*)lds;
  const uint32_t aFragBase = (uint32_t)waveM * 8192u + (uint32_t)mrow * 64u + (uint32_t)xs;
  const uint32_t bFragBase = LDS_B_OFF + (uint32_t)waveN * 4096u
                           + (uint32_t)mrow * 64u + (uint32_t)xs;
  const uint32_t aA0 = ldsBase + aFragBase;
  const uint32_t aA1 = aA0 + LDS_BUF;
  const uint32_t bA0 = ldsBase + bFragBase;
  const uint32_t bA1 = bA0 + LDS_BUF;

  const uint32_t srow  = (uint32_t)wid * 32u + (uint32_t)(lane >> 2);
  const uint32_t slot  = (uint32_t)(tid & 3);
  const uint32_t chnk  = slot ^ ((srow >> 1) & 3u);   // pre-swizzled chunk
  // R3-verified staging offset: wave w owns [w*2048, w*2048+2048).
  const uint32_t ldsSt = (uint32_t)(tid >> 6) * 2048u
                       + (uint32_t)(tid & 63) * 16u;
  const char* Ab = (const char*)xb;
  const char* Bb = (const char*)tern;

  floatx4 a0f[4], a1f[4], b0f[4], b1f[4];
  floatx4 acc[8][4];

#define DSR(DST, ADDR, IMM)                                                \
  asm volatile("ds_read_b128 %0, %1 offset:%c2"                            \
               : "=v"(DST) : "v"(ADDR), "i"(IMM))

#define IA4(DST, ADDR, KC, MH) do {                                        \
    DSR(DST[0], ADDR, (KC) * 16384 + ((MH) * 4 + 0) * 1024);               \
    DSR(DST[1], ADDR, (KC) * 16384 + ((MH) * 4 + 1) * 1024);               \
    DSR(DST[2], ADDR, (KC) * 16384 + ((MH) * 4 + 2) * 1024);               \
    DSR(DST[3], ADDR, (KC) * 16384 + ((MH) * 4 + 3) * 1024);               \
  } while (0)

#define IB2(DST, N0, ADDR, KC) do {                                        \
    DSR(DST[N0],     ADDR, (KC) * 16384 + ((N0)) * 1024);                  \
    DSR(DST[N0 + 1], ADDR, (KC) * 16384 + ((N0) + 1) * 1024);              \
  } while (0)

#define STAGE_A(BUF, KH, KB) do {                                          \
    uint32_t g_ = stA + (KB) + (KH) * 64u;                                 \
    uint32_t l_ = (BUF) * LDS_BUF + (KH) * LDS_KC + ldsSt;                 \
    async_copy16(Ab + g_,           lds + l_);                             \
    async_copy16(Ab + g_ + 131072u, lds + l_ + 1024u);                     \
  } while (0)

#define STAGE_B(BUF, KH, KB) do {                                          \
    uint32_t g_ = stB + (KB) + (KH) * 64u;                                 \
    uint32_t l_ = (BUF) * LDS_BUF + LDS_B_OFF + (KH) * LDS_KC + ldsSt;     \
    async_copy16(Bb + g_,           lds + l_);                             \
    async_copy16(Bb + g_ + 131072u, lds + l_ + 1024u);                     \
  } while (0)

#define PHASE(MH, AF, BF, ISSUE_STMT, STAGE_STMT) do {                     \
    asm volatile("s_waitcnt lgkmcnt(0)" ::: "memory");                     \
    asm volatile("s_waitcnt vmcnt(8)" ::: "memory");                       \
    __builtin_amdgcn_sched_barrier(0);                                     \
    ISSUE_STMT;                                                            \
    __builtin_amdgcn_sched_barrier(0);                                     \
    __builtin_amdgcn_s_setprio(1);                                         \
    _Pragma("unroll")                                                      \
    for (int m_ = 0; m_ < 4; ++m_)                                         \
      _Pragma("unroll")                                                    \
      for (int n_ = 0; n_ < 4; ++n_)                                       \
        acc[(MH) * 4 + m_][n_] = __builtin_amdgcn_mfma_f32_16x16x32_bf16(  \
            __builtin_bit_cast(bf16x8, AF[m_]),                            \
            __builtin_bit_cast(bf16x8, BF[n_]),                            \
            acc[(MH) * 4 + m_][n_], 0, 0, 0);                              \
    __builtin_amdgcn_s_setprio(0);                                         \
    STAGE_STMT;                                                            \
    __builtin_amdgcn_s_barrier();                                          \
  } while (0)

#pragma unroll 1
  for (int t = 0; t < 2; ++t) {
    // Bijective XCD swizzle over 512 logical tiles (9-bit bijection);
    // t=0/t=1 share bn (B-panel L2 reuse within a block).
    const uint32_t flat = b + (uint32_t)t * 256u;
    const uint32_t swz  = ((flat & 7u) << 6) | (flat >> 3);
    const uint32_t bm = (swz >> 4) * 256u;
    const uint32_t bn = (swz & 15u) * 256u;
    const uint32_t stA = (bm + srow) * (DIN * 2u) + chnk * 16u;
    const uint32_t stB = (bn + srow) * (DIN * 2u) + chnk * 16u;

#pragma unroll
    for (int m = 0; m < 8; ++m)
#pragma unroll
      for (int n = 0; n < 4; ++n)
        acc[m][n] = (floatx4)0.0f;

    // Tile-boundary drain: retire dangling ds_reads and ALL in-flight DMA
    // (incl. wrapped garbage stages) before re-staging the same regions.
    asm volatile("s_waitcnt lgkmcnt(0)" ::: "memory");
    asm volatile("s_waitcnt vmcnt(0)" ::: "memory");
    __builtin_amdgcn_s_barrier();

    // Prologue: 7 regions in steady-state stage order.
    STAGE_B(0, 0, 0u);    // b0.Bk0
    STAGE_A(0, 0, 0u);    // b0.Ak0
    STAGE_B(0, 1, 0u);    // b0.Bk1
    STAGE_A(0, 1, 0u);    // b0.Ak1
    STAGE_B(1, 0, 128u);  // b1.Bk0
    STAGE_A(1, 0, 128u);  // b1.Ak0
    STAGE_B(1, 1, 128u);  // b1.Bk1
    asm volatile("s_waitcnt vmcnt(8)" ::: "memory");   // b0.kc0 landed
    __builtin_amdgcn_s_barrier();
    // Prime bank for Ph1's MFMA.
    IB2(b0f, 0, bA0, 0); IB2(b0f, 2, bA0, 0);
    IA4(a0f, aA0, 0, 0);

#pragma unroll 1
    for (int i = 0; i < 32; ++i) {
      const uint32_t kb1 = (uint32_t)(2 * i + 1) * 128u;
      const uint32_t kb2 = (uint32_t)((2 * i + 2) & 63) * 128u;  // wraps: valid mem, never read
      const uint32_t kb3 = (uint32_t)((2 * i + 3) & 63) * 128u;

      PHASE(0, a0f, b0f, { IA4(a1f, aA0, 0, 1); IB2(b1f, 0, bA0, 1); },
            STAGE_A(1, 1, kb1));                                          // Ph1
      PHASE(1, a1f, b0f, { IA4(a0f, aA0, 1, 0); IB2(b1f, 2, bA0, 1); },
            STAGE_B(0, 0, kb2));                                          // Ph2
      PHASE(0, a0f, b1f, { IA4(a1f, aA0, 1, 1); IB2(b0f, 0, bA1, 0); },
            STAGE_A(0, 0, kb2));                                          // Ph3
      PHASE(1, a1f, b1f, { IA4(a0f, aA1, 0, 0); IB2(b0f, 2, bA1, 0); },
            STAGE_B(0, 1, kb2));                                          // Ph4
      PHASE(0, a0f, b0f, { IA4(a1f, aA1, 0, 1); IB2(b1f, 0, bA1, 1); },
            STAGE_A(0, 1, kb2));                                          // Ph5
      PHASE(1, a1f, b0f, { IA4(a0f, aA1, 1, 0); IB2(b1f, 2, bA1, 1); },
            STAGE_B(1, 0, kb3));                                          // Ph6
      PHASE(0, a0f, b1f, { IA4(a1f, aA1, 1, 1); IB2(b0f, 0, bA0, 0); },
            STAGE_A(1, 0, kb3));                                          // Ph7
      PHASE(1, a1f, b1f, { IA4(a0f, aA0, 0, 0); IB2(b0f, 2, bA0, 0); },
            STAGE_B(1, 1, kb3));                                          // Ph8
    }

    // C/D layout: col = lane&15, row = (lane>>4)*4 + reg.
    const int col0 = (int)bn + waveN * 64 + (lane & 15);
    const int row0 = (int)bm + waveM * 128 + (lane >> 4) * 4;
    float* Cp = C + (size_t)row0 * DOUT + col0;
#pragma unroll
    for (int m = 0; m < 8; ++m)
#pragma unroll
      for (int n = 0; n < 4; ++n)
#pragma unroll
        for (int r = 0; r < 4; ++r)
          Cp[(size_t)(m * 16 + r) * DOUT + n * 16] = acc[m][n][r];
  }

#undef DSR
#undef IA4
#undef IB2
#undef STAGE_A
#undef STAGE_B
#undef PHASE
}

extern "C" void kernel_launch(void* const* d_in, const int* in_sizes, int n_in,
                              void* d_out, int out_size, void* d_ws, size_t ws_size,
                              hipStream_t stream) {
  const float* x  = (const float*)d_in[0];   // [8192, 4096] fp32
  const float* wp = (const float*)d_in[1];   // [4096, 4096] fp32
  const float* wn = (const float*)d_in[2];   // [4096, 4096] fp32
  float* out = (float*)d_out;                // [8192, 4096] fp32

  unsigned short* xb   = (unsigned short*)d_ws;
  unsigned short* tern = xb + (size_t)TOKENS * DIN;

  // Cooperative launch: 256 blocks x 512 threads, 1 block/CU (128 KiB
  // LDS), exactly all co-resident -> this_grid().sync() is valid.
  void* args[6] = {
      (void*)&x, (void*)&wp, (void*)&wn,
      (void*)&xb, (void*)&tern, (void*)&out,
  };
  (void)hipLaunchCooperativeKernel((const void*)fused_kernel,
                                   dim3(256), dim3(512), args, 0, stream);
}